// Round 1
// 234.095 us; speedup vs baseline: 1.2430x; 1.2430x over previous
//
#include <hip/hip_runtime.h>
#include <hip/hip_fp16.h>

#define Hh 1024
#define Ww 1024
#define PO 12        // halo offset (>= T+2)
#define PS 1048      // padded row stride = 1024 + 2*PO
#define T 10         // fused iterations per launch (100 = 10 launches x 10)
#define TILE 32      // output tile per block
#define RG 52        // region = TILE + 2T
#define XSH 54       // LDS row stride in px (half2 = 4B; EVEN -> uint2 aligned)
#define NPX (RG * RG)  // 2704 region pixels

typedef unsigned int u32;

// packed per-pixel weights: 8 x fp16 in one 16B struct (w0..w7)
struct alignas(16) W8 { __half2 a, b, c, d; };

__device__ inline __half2 h2(u32 v) { return *(__half2*)&v; }
__device__ inline u32 u2(__half2 v) { return *(u32*)&v; }

// R13: packed-weight FMA. w holds TWO weights (lo,hi). op_sel broadcasts the
// selected half of w across both lanes of the packed fma:
//   fma_lo: acc.l += w.l*x.l ; acc.h += w.l*x.h   (op_sel_hi[0]=0)
//   fma_hi: acc.l += w.h*x.l ; acc.h += w.h*x.h   (op_sel[0]=1)
// This halves weight register count (80 -> 40 u32) and removes the per-launch
// unpack pass. Pure VALU asm, register-only: no waitcnt/ordering hazards.
__device__ inline void fma_lo(u32& acc, u32 w, u32 x) {
    asm("v_pk_fma_f16 %0, %1, %2, %0 op_sel_hi:[0,1,1]"
        : "+v"(acc) : "v"(w), "v"(x));
}
__device__ inline void fma_hi(u32& acc, u32 w, u32 x) {
    asm("v_pk_fma_f16 %0, %1, %2, %0 op_sel:[1,0,0] op_sel_hi:[1,1,1]"
        : "+v"(acc) : "v"(w), "v"(x));
}

// address-space typedefs for global_load_lds (async global->LDS DMA)
typedef __attribute__((address_space(3))) u32 lds_u32_t;
typedef __attribute__((address_space(1))) const u32 glb_u32_t;

// ---------------------------------------------------------------------------
// prep: Ypad (luma, zero halo), x0 = b as half2 (IQ if colored else 0, zero
// halo), x1 = 0, mask (isColored).
// ---------------------------------------------------------------------------
__global__ __launch_bounds__(256)
void prep_kernel(const float* __restrict__ gray, const float* __restrict__ app,
                 float* __restrict__ Ypad, u32* __restrict__ x0,
                 u32* __restrict__ x1, unsigned char* __restrict__ mask) {
    int px = blockIdx.x * 64 + threadIdx.x;
    int py = blockIdx.y * 4 + threadIdx.y;
    if (px >= PS || py >= PS) return;
    int p = py * PS + px;
    int i = py - PO, j = px - PO;
    float yv = 0.f;
    float2 bv = make_float2(0.f, 0.f);
    if (i >= 0 && i < Hh && j >= 0 && j < Ww) {
        int idx = i * Ww + j;
        const float s = 1.f / 255.f;
        float gr = gray[idx * 3 + 0] * s;
        float gg = gray[idx * 3 + 1] * s;
        float gb = gray[idx * 3 + 2] * s;
        float ar = app[idx * 3 + 0] * s;
        float ag = app[idx * 3 + 1] * s;
        float ab = app[idx * 3 + 2] * s;
        float diff = fabsf(gr - ar) + fabsf(gg - ag) + fabsf(gb - ab);
        bool colored = diff > 0.01f;
        yv = 0.3f * gr + 0.59f * gg + 0.11f * gb;
        float ay = 0.3f * ar + 0.59f * ag + 0.11f * ab;
        float ai = 0.74f * (ar - ay) - 0.27f * (ab - ay);
        float aq = 0.48f * (ar - ay) + 0.41f * (ab - ay);
        if (colored) bv = make_float2(ai, aq);
        mask[idx] = colored ? 1 : 0;
    }
    Ypad[p] = yv;
    __half2 h = __floats2half2_rn(bv.x, bv.y);
    x0[p] = u2(h);
    x1[p] = 0u;                 // half2(0,0)
}

// ---------------------------------------------------------------------------
// weights: per padded pixel, 8 normalized neighbor weights packed fp16 (16B).
// Outside the image: all zero. Colored pixel: all zero except sign bit on w0
// (-0.0h = "keep center").
// ---------------------------------------------------------------------------
__global__ __launch_bounds__(256)
void weights_kernel(const float* __restrict__ Ypad,
                    const unsigned char* __restrict__ mask,
                    W8* __restrict__ w) {
    int px = blockIdx.x * 64 + threadIdx.x;
    int py = blockIdx.y * 4 + threadIdx.y;
    if (px >= PS || py >= PS) return;
    int p = py * PS + px;
    int i = py - PO, j = px - PO;
    W8 out;
    out.a = __floats2half2_rn(0.f, 0.f);
    out.b = out.a; out.c = out.a; out.d = out.a;
    if (i >= 0 && i < Hh && j >= 0 && j < Ww) {
        float yc = Ypad[p];
        float yn[8];
        yn[0] = Ypad[p - PS - 1]; yn[1] = Ypad[p - PS]; yn[2] = Ypad[p - PS + 1];
        yn[3] = Ypad[p - 1];                            yn[4] = Ypad[p + 1];
        yn[5] = Ypad[p + PS - 1]; yn[6] = Ypad[p + PS]; yn[7] = Ypad[p + PS + 1];
        float vt = (i > 0) ? 1.f : 0.f;
        float vb = (i < Hh - 1) ? 1.f : 0.f;
        float vl = (j > 0) ? 1.f : 0.f;
        float vr = (j < Ww - 1) ? 1.f : 0.f;
        float v[8] = { vt * vl, vt, vt * vr, vl, vr, vb * vl, vb, vb * vr };

        float count = 1.f, s1 = yc;
#pragma unroll
        for (int k = 0; k < 8; ++k) { count += v[k]; s1 += v[k] * yn[k]; }
        float mean = s1 / count;
        float var = (yc - mean) * (yc - mean);
#pragma unroll
        for (int k = 0; k < 8; ++k) { float d = yn[k] - mean; var += v[k] * d * d; }
        var /= count;
        float vs = fmaxf(0.6f * var, 2e-6f);
        float inv_vs = 1.f / vs;

        float wk[8], ws = 0.f;
#pragma unroll
        for (int k = 0; k < 8; ++k) {
            float d = yn[k] - yc;
            wk[k] = v[k] * expf(-d * d * inv_vs);
            ws += wk[k];
        }
        if (mask[i * Ww + j]) {
            out.a = __floats2half2_rn(-0.0f, 0.f);  // sign bit => keep center
        } else {
            float scale = 1.f / ws;
            out.a = __floats2half2_rn(wk[0] * scale, wk[1] * scale);
            out.b = __floats2half2_rn(wk[2] * scale, wk[3] * scale);
            out.c = __floats2half2_rn(wk[4] * scale, wk[5] * scale);
            out.d = __floats2half2_rn(wk[6] * scale, wk[7] * scale);
        }
    }
    w[p] = out;
}

// ---------------------------------------------------------------------------
// iter10p: T=10 temporal-tiled register-window stencil, packed fp16 math.
// R13 changes vs R12:
//  (1) XCD-aware block swizzle: each of the 8 XCDs gets a contiguous band of
//      4 tile-rows (128 blocks). Per-XCD weight working set = ~150 rows x
//      1048 x 16B = 2.5 MB < 4 MB L2, and the swizzle is deterministic so the
//      band stays L2-resident across all 10 launches.
//  (2) Weights stay PACKED (4 u32/px, 8 fp16) and are applied with
//      v_pk_fma_f16 op_sel broadcasts: -40 VGPR, no unpack pass.
//  (3) "keep center" masks (sign bit of w0) precomputed once into kL/kR,
//      inner-loop init is a single v_and instead of test+cndmask per acc.
// Inner-loop math is bit-identical to R12 (same fp16 fma sequence).
// ---------------------------------------------------------------------------
__global__ __launch_bounds__(256, 4)
void iter10p_kernel(const u32* __restrict__ xin, u32* __restrict__ xout,
                    const W8* __restrict__ w, const float* __restrict__ Ypad,
                    float* __restrict__ out, int writeRGB) {
    __shared__ __align__(16) u32 xsm[2][RG * XSH];   // 22.5 KB
    int tid = threadIdx.x;

    // XCD swizzle: grid is fixed 32x32 = 1024 blocks, 8 XCDs, 1024%8==0 so
    // the remap is bijective. Original bid%8 ~ XCD id (round-robin dispatch);
    // give XCD k the contiguous band nbid in [k*128, (k+1)*128).
    int bid  = (int)blockIdx.y * 32 + (int)blockIdx.x;
    int nbid = (bid & 7) * 128 + (bid >> 3);
    int gi0 = (nbid >> 5) * TILE - T;
    int gj0 = (nbid & 31) * TILE - T;

    // async stage: wave wv stages rows wv*13 .. wv*13+12; lane ln carries px ln
    {
        int wv = tid >> 6;
        int ln = tid & 63;
        if (ln < RG) {
            const u32* gbase = xin + (size_t)(gi0 + wv * 13 + PO) * PS + (gj0 + PO) + ln;
#pragma unroll 1
            for (int k = 0; k < 13; ++k) {
                __builtin_amdgcn_global_load_lds((glb_u32_t*)(gbase + (size_t)k * PS),
                                                 (lds_u32_t*)&xsm[0][(wv * 13 + k) * XSH],
                                                 4, 0, 0);
            }
        }
    }

    // 250 active threads: strip s = tid/25 -> rows r0=1+5s..r0+4 (in [1,50]);
    // cp = tid%25 -> cols c0=1+2cp, c0+1 (c0 odd => c0-1 even, uint2 aligned)
    bool active = tid < 250;
    int s  = tid / 25;
    int cp = tid - s * 25;
    int r0 = 1 + 5 * s;
    int c0 = 1 + 2 * cp;

    // weights: 10 px/thread, PACKED: 8 u32 per row-pair (4 for left px, 4 for
    // right px). 40 u32 total + 10 u32 keep-masks. These VMEM loads overlap
    // the staging DMA above.
    u32 wq[5][8];
    u32 kL[5], kR[5];
    if (active) {
#pragma unroll
        for (int i = 0; i < 5; ++i) {
            int gp = (gi0 + r0 + i + PO) * PS + (gj0 + c0 + PO);
            const uint4* wp = (const uint4*)(w + gp);
            uint4 wa = wp[0];
            uint4 wb = wp[1];
            wq[i][0] = wa.x; wq[i][1] = wa.y; wq[i][2] = wa.z; wq[i][3] = wa.w;
            wq[i][4] = wb.x; wq[i][5] = wb.y; wq[i][6] = wb.z; wq[i][7] = wb.w;
            // sign bit of w0 (lo half of first u32) => colored px, keep center
            kL[i] = (wa.x & 0x8000u) ? 0xFFFFFFFFu : 0u;
            kR[i] = (wb.x & 0x8000u) ? 0xFFFFFFFFu : 0u;
        }
    }
    __syncthreads();   // drains the DMA (vmcnt) + makes staged region visible

    int cur = 0;
#pragma unroll 1
    for (int t = 0; t < T; ++t) {        // rolled: no t-dependence inside
        int nxt = cur ^ 1;
        if (active) {
            const uint2* rp;
            uint2 u0, u1, m0, m1;
            rp = (const uint2*)&xsm[cur][(r0 - 1) * XSH]; u0 = rp[cp]; u1 = rp[cp + 1];
            rp = (const uint2*)&xsm[cur][r0 * XSH];       m0 = rp[cp]; m1 = rp[cp + 1];
#pragma unroll
            for (int i = 0; i < 5; ++i) {
                uint2 d0, d1;
                rp = (const uint2*)&xsm[cur][(r0 + i + 1) * XSH];
                d0 = rp[cp]; d1 = rp[cp + 1];

                // keep-center init: mask & center (old value) or 0
                u32 accL = kL[i] & m0.y;
                fma_lo(accL, wq[i][0], u0.x);   // w0 * (-1,-1)
                fma_hi(accL, wq[i][0], u0.y);   // w1 * (-1, 0)
                fma_lo(accL, wq[i][1], u1.x);   // w2 * (-1,+1)
                fma_hi(accL, wq[i][1], m0.x);   // w3 * ( 0,-1)
                fma_lo(accL, wq[i][2], m1.x);   // w4 * ( 0,+1)
                fma_hi(accL, wq[i][2], d0.x);   // w5 * (+1,-1)
                fma_lo(accL, wq[i][3], d0.y);   // w6 * (+1, 0)
                fma_hi(accL, wq[i][3], d1.x);   // w7 * (+1,+1)

                u32 accR = kR[i] & m1.x;
                fma_lo(accR, wq[i][4], u0.y);
                fma_hi(accR, wq[i][4], u1.x);
                fma_lo(accR, wq[i][5], u1.y);
                fma_hi(accR, wq[i][5], m0.y);
                fma_lo(accR, wq[i][6], m1.y);
                fma_hi(accR, wq[i][6], d0.y);
                fma_lo(accR, wq[i][7], d1.x);
                fma_hi(accR, wq[i][7], d1.y);

                int wp2 = (r0 + i) * XSH + c0;
                xsm[nxt][wp2]     = accL;
                xsm[nxt][wp2 + 1] = accR;

                u0 = m0; u1 = m1; m0 = d0; m1 = d1;  // slide window
            }
        }
        __syncthreads();
        cur = nxt;
    }

    if (!writeRGB) {
        // write central 32x32 tile (region rows/cols 10..41) as half2
#pragma unroll
        for (int k = 0; k < 4; ++k) {
            int pidx = tid + k * 256;
            int r = T + (pidx >> 5), c = T + (pidx & 31);
            xout[(gi0 + r + PO) * PS + (gj0 + c + PO)] = xsm[cur][r * XSH + c];
        }
    } else {
        // fused final: yiq -> rgb, clip, *255 straight from LDS
#pragma unroll
        for (int k = 0; k < 4; ++k) {
            int pidx = tid + k * 256;
            int r = T + (pidx >> 5), c = T + (pidx & 31);
            int gi = gi0 + r, gj = gj0 + c;
            float y = Ypad[(gi + PO) * PS + (gj + PO)];
            u32 pxv = xsm[cur][r * XSH + c];
            float2 iq = __half22float2(h2(pxv));
            float R_ = y + 0.9468822170900693f * iq.x + 0.6235565819861433f * iq.y;
            float G_ = y - 0.27478764629897834f * iq.x - 0.6356910791873801f * iq.y;
            float B_ = y - 1.1085450346420322f * iq.x + 1.7090069284064666f * iq.y;
            int idx = gi * Ww + gj;
            out[idx * 3 + 0] = fminf(fmaxf(R_, 0.f), 1.f) * 255.f;
            out[idx * 3 + 1] = fminf(fmaxf(G_, 0.f), 1.f) * 255.f;
            out[idx * 3 + 2] = fminf(fmaxf(B_, 0.f), 1.f) * 255.f;
        }
    }
}

extern "C" void kernel_launch(void* const* d_in, const int* in_sizes, int n_in,
                              void* d_out, int out_size, void* d_ws, size_t ws_size,
                              hipStream_t stream) {
    const float* gray = (const float*)d_in[0];
    const float* app  = (const float*)d_in[1];
    float* out = (float*)d_out;

    char* ws = (char*)d_ws;
    size_t off = 0;
    auto alloc = [&](size_t bytes) -> void* {
        void* r = ws + off;
        off = (off + bytes + 255) & ~(size_t)255;
        return r;
    };
    float* Ypad = (float*)alloc((size_t)PS * PS * sizeof(float));
    W8*    w    = (W8*)   alloc((size_t)PS * PS * sizeof(W8));
    unsigned char* mask = (unsigned char*)alloc((size_t)Hh * Ww);
    u32*   x0   = (u32*)  alloc((size_t)PS * PS * sizeof(u32));
    u32*   x1   = (u32*)  alloc((size_t)PS * PS * sizeof(u32));

    dim3 blk(64, 4);
    dim3 gridPad((PS + 63) / 64, (PS + 3) / 4);
    prep_kernel<<<gridPad, blk, 0, stream>>>(gray, app, Ypad, x0, x1, mask);
    weights_kernel<<<gridPad, blk, 0, stream>>>(Ypad, mask, w);

    dim3 gridIter(Ww / TILE, Hh / TILE);  // 32 x 32 = 1024 blocks (4 per CU)
    u32* xin = x0;
    u32* xout = x1;
    for (int l = 0; l < 10; ++l) {        // 10 x 10 = 100 iterations
        int last = (l == 9) ? 1 : 0;
        iter10p_kernel<<<gridIter, 256, 0, stream>>>(xin, xout, w, Ypad, out, last);
        u32* tmp = xin; xin = xout; xout = tmp;
    }
}